// Round 13
// baseline (1247.460 us; speedup 1.0000x reference)
//
#include <hip/hip_runtime.h>

#define NEGV (-10000.0f)

static constexpr int Bb    = 128;
static constexpr int Tt    = 512;
static constexpr int Mrows = Bb * Tt;   // 65536
static constexpr int Hh    = 50;
static constexpr int START = 5;

typedef __attribute__((ext_vector_type(8))) short bf16x8;
typedef __attribute__((ext_vector_type(4))) float f32x4;
typedef __attribute__((ext_vector_type(2))) _Float16 h2t;

__device__ __forceinline__ float fsig(float x) {
    return __builtin_amdgcn_rcpf(1.0f + __expf(-x));
}
__device__ __forceinline__ float ftanh(float x) {
    return 2.0f * __builtin_amdgcn_rcpf(1.0f + __expf(-2.0f * x)) - 1.0f;
}
__device__ __forceinline__ unsigned short f2bf(float f) {
    unsigned u = __float_as_uint(f);
    u = (u + 0x7fffu + ((u >> 16) & 1u)) >> 16;   // RNE
    return (unsigned short)u;
}
#define BF(u) __uint_as_float(((unsigned)(u)) << 16)

// ---------------------------------------------------------------------------
// Convert W [400][K] fp32 -> [448][KP] bf16 (zero-padded rows/cols)
// ---------------------------------------------------------------------------
__global__ __launch_bounds__(256) void conv_w(
    const float* __restrict__ src, unsigned short* __restrict__ dst,
    int K, int KP)
{
    int gid = blockIdx.x * 256 + threadIdx.x;
    int tot = 448 * KP;
    if (gid >= tot) return;
    int r = gid / KP, c = gid % KP;
    float v = (r < 400 && c < K) ? src[r * K + c] : 0.f;
    dst[gid] = f2bf(v);
}

// ---------------------------------------------------------------------------
// Convert A rows (optionally gathered) fp32 -> [M][KP] bf16, 8 cols/thread
// ---------------------------------------------------------------------------
template <bool GATHER>
__global__ __launch_bounds__(256) void conv_a(
    const float* __restrict__ src, const int* __restrict__ idx,
    unsigned short* __restrict__ dst, int K, int KP, int cpr)
{
    long gid = (long)blockIdx.x * 256 + threadIdx.x;
    long tot = (long)Mrows * cpr;
    if (gid >= tot) return;
    long m = gid / cpr;
    int p = (int)(gid - m * cpr) * 8;
    const float* s = src + (GATHER ? (long)idx[m] : m) * K;
    unsigned u0, u1, u2, u3;
    {
        float x0 = (p + 0 < K) ? s[p + 0] : 0.f;
        float x1 = (p + 1 < K) ? s[p + 1] : 0.f;
        float x2 = (p + 2 < K) ? s[p + 2] : 0.f;
        float x3 = (p + 3 < K) ? s[p + 3] : 0.f;
        float x4 = (p + 4 < K) ? s[p + 4] : 0.f;
        float x5 = (p + 5 < K) ? s[p + 5] : 0.f;
        float x6 = (p + 6 < K) ? s[p + 6] : 0.f;
        float x7 = (p + 7 < K) ? s[p + 7] : 0.f;
        u0 = (unsigned)f2bf(x0) | ((unsigned)f2bf(x1) << 16);
        u1 = (unsigned)f2bf(x2) | ((unsigned)f2bf(x3) << 16);
        u2 = (unsigned)f2bf(x4) | ((unsigned)f2bf(x5) << 16);
        u3 = (unsigned)f2bf(x6) | ((unsigned)f2bf(x7) << 16);
    }
    uint4 v = make_uint4(u0, u1, u2, u3);
    *(uint4*)(dst + m * KP + p) = v;
}

// ---------------------------------------------------------------------------
// bf16 MFMA GEMM: C[M,400]bf16 = A[M,KP]bf16 @ W[448,KP]bf16^T + bias
// (unchanged from r10/r11, verified)
// ---------------------------------------------------------------------------
__global__ __launch_bounds__(256) void gemm_mfma(
    const unsigned short* __restrict__ Ab,   // [M][KP]
    const unsigned short* __restrict__ Wb,   // [448][KP]
    const float* __restrict__ bias,          // [400]
    unsigned short* __restrict__ C,          // [M][400] bf16
    int KP)
{
    __shared__ unsigned short As[128][40];
    __shared__ unsigned short Ws[64][40];

    const int tid = threadIdx.x;
    const int m0 = blockIdx.x * 128;
    const int n0 = blockIdx.y * 64;

    const int w  = tid >> 6, l = tid & 63;
    const int wm = (w >> 1) * 64;
    const int wn = (w & 1) * 32;
    const int lr = l & 15;
    const int lk = (l >> 4) * 8;

    f32x4 acc[4][2] = {};

    for (int k0 = 0; k0 < KP; k0 += 32) {
        __syncthreads();
        {
            int c = tid;
            int r = c >> 2, p = (c & 3) * 8;
            *(bf16x8*)&As[r][p] = *(const bf16x8*)(Ab + (long)(m0 + r) * KP + k0 + p);
            c = tid + 256;
            r = c >> 2; p = (c & 3) * 8;
            *(bf16x8*)&As[r][p] = *(const bf16x8*)(Ab + (long)(m0 + r) * KP + k0 + p);
            r = tid >> 2; p = (tid & 3) * 8;
            *(bf16x8*)&Ws[r][p] = *(const bf16x8*)(Wb + (long)(n0 + r) * KP + k0 + p);
        }
        __syncthreads();

        bf16x8 af0 = *(const bf16x8*)&As[wm +  0 + lr][lk];
        bf16x8 af1 = *(const bf16x8*)&As[wm + 16 + lr][lk];
        bf16x8 af2 = *(const bf16x8*)&As[wm + 32 + lr][lk];
        bf16x8 af3 = *(const bf16x8*)&As[wm + 48 + lr][lk];
        bf16x8 wf0 = *(const bf16x8*)&Ws[wn +  0 + lr][lk];
        bf16x8 wf1 = *(const bf16x8*)&Ws[wn + 16 + lr][lk];

        acc[0][0] = __builtin_amdgcn_mfma_f32_16x16x32_bf16(af0, wf0, acc[0][0], 0, 0, 0);
        acc[0][1] = __builtin_amdgcn_mfma_f32_16x16x32_bf16(af0, wf1, acc[0][1], 0, 0, 0);
        acc[1][0] = __builtin_amdgcn_mfma_f32_16x16x32_bf16(af1, wf0, acc[1][0], 0, 0, 0);
        acc[1][1] = __builtin_amdgcn_mfma_f32_16x16x32_bf16(af1, wf1, acc[1][1], 0, 0, 0);
        acc[2][0] = __builtin_amdgcn_mfma_f32_16x16x32_bf16(af2, wf0, acc[2][0], 0, 0, 0);
        acc[2][1] = __builtin_amdgcn_mfma_f32_16x16x32_bf16(af2, wf1, acc[2][1], 0, 0, 0);
        acc[3][0] = __builtin_amdgcn_mfma_f32_16x16x32_bf16(af3, wf0, acc[3][0], 0, 0, 0);
        acc[3][1] = __builtin_amdgcn_mfma_f32_16x16x32_bf16(af3, wf1, acc[3][1], 0, 0, 0);
    }

    const int orow = (l >> 4) * 4;
    const int ocol = l & 15;
    #pragma unroll
    for (int a = 0; a < 4; ++a) {
        #pragma unroll
        for (int bb = 0; bb < 2; ++bb) {
            const int col = n0 + wn + bb * 16 + ocol;
            if (col < 400) {
                const float bv = bias[col];
                #pragma unroll
                for (int i = 0; i < 4; ++i) {
                    const long row = m0 + wm + a * 16 + orow + i;
                    C[row * 400 + col] = f2bf(acc[a][bb][i] + bv);
                }
            }
        }
    }
}

// ---------------------------------------------------------------------------
// LSTM scan: ONE WAVE per (b,dir). Lane u<50 owns unit u end-to-end:
// all 4 gate rows as 100 packed-half2 uints. Zero LDS / zero barriers.
// h shared via 25 readlane of packed h2 (re-packed per step with 2
// ds_bpermute + v_cvt_pkrtz, bit_cast'd to our h2t — the r12 compile
// failure was the missing bit_cast). Dot products via v_dot2_f32_f16.
// ---------------------------------------------------------------------------
#if __has_builtin(__builtin_amdgcn_fdot2)
#define DOT2(W, HH, A) A = __builtin_amdgcn_fdot2(W, HH, A, false)
#else
#define DOT2(W, HH, A) A += (float)(W).x * (float)(HH).x + (float)(W).y * (float)(HH).y
#endif

#define LDW(P, Q) __builtin_bit_cast(unsigned, (h2t){(_Float16)(P)[2*(Q)], (_Float16)(P)[2*(Q)+1]})
#define PKH(A, B) __builtin_bit_cast(h2t, __builtin_amdgcn_cvt_pkrtz((A), (B)))
#define LA10(x0,x1,x2,x3,x4,x5,x6,x7,x8,x9) \
    asm volatile("" : "+v"(x0), "+v"(x1), "+v"(x2), "+v"(x3), "+v"(x4), \
                      "+v"(x5), "+v"(x6), "+v"(x7), "+v"(x8), "+v"(x9))

__global__ void
__attribute__((amdgpu_flat_work_group_size(64, 64), amdgpu_waves_per_eu(1, 1)))
lstm_scan(
    const unsigned short* __restrict__ xg,  // [M,400] bf16 (bias added)
    const float* __restrict__ w_hh,         // [2,200,50]
    const float* __restrict__ h0,           // layer base: [2,B,50]
    const float* __restrict__ c0,
    float* __restrict__ xout)               // [M,100] fp32
{
    const int b    = blockIdx.x & 127;
    const int dir  = blockIdx.x >> 7;
    const int lane = threadIdx.x;
    const int u    = (lane < 50) ? lane : 49;

    const float* r0 = w_hh + (long)dir * 10000 + (long)u * 50;  // i row
    const float* r1 = r0 + 2500;                                // f
    const float* r2 = r0 + 5000;                                // g
    const float* r3 = r0 + 7500;                                // o

    unsigned wi0=LDW(r0,0),wi1=LDW(r0,1),wi2=LDW(r0,2),wi3=LDW(r0,3),wi4=LDW(r0,4);
    unsigned wi5=LDW(r0,5),wi6=LDW(r0,6),wi7=LDW(r0,7),wi8=LDW(r0,8),wi9=LDW(r0,9);
    unsigned wi10=LDW(r0,10),wi11=LDW(r0,11),wi12=LDW(r0,12),wi13=LDW(r0,13),wi14=LDW(r0,14);
    unsigned wi15=LDW(r0,15),wi16=LDW(r0,16),wi17=LDW(r0,17),wi18=LDW(r0,18),wi19=LDW(r0,19);
    unsigned wi20=LDW(r0,20),wi21=LDW(r0,21),wi22=LDW(r0,22),wi23=LDW(r0,23),wi24=LDW(r0,24);
    unsigned wf0=LDW(r1,0),wf1=LDW(r1,1),wf2=LDW(r1,2),wf3=LDW(r1,3),wf4=LDW(r1,4);
    unsigned wf5=LDW(r1,5),wf6=LDW(r1,6),wf7=LDW(r1,7),wf8=LDW(r1,8),wf9=LDW(r1,9);
    unsigned wf10=LDW(r1,10),wf11=LDW(r1,11),wf12=LDW(r1,12),wf13=LDW(r1,13),wf14=LDW(r1,14);
    unsigned wf15=LDW(r1,15),wf16=LDW(r1,16),wf17=LDW(r1,17),wf18=LDW(r1,18),wf19=LDW(r1,19);
    unsigned wf20=LDW(r1,20),wf21=LDW(r1,21),wf22=LDW(r1,22),wf23=LDW(r1,23),wf24=LDW(r1,24);
    unsigned wg0=LDW(r2,0),wg1=LDW(r2,1),wg2=LDW(r2,2),wg3=LDW(r2,3),wg4=LDW(r2,4);
    unsigned wg5=LDW(r2,5),wg6=LDW(r2,6),wg7=LDW(r2,7),wg8=LDW(r2,8),wg9=LDW(r2,9);
    unsigned wg10=LDW(r2,10),wg11=LDW(r2,11),wg12=LDW(r2,12),wg13=LDW(r2,13),wg14=LDW(r2,14);
    unsigned wg15=LDW(r2,15),wg16=LDW(r2,16),wg17=LDW(r2,17),wg18=LDW(r2,18),wg19=LDW(r2,19);
    unsigned wg20=LDW(r2,20),wg21=LDW(r2,21),wg22=LDW(r2,22),wg23=LDW(r2,23),wg24=LDW(r2,24);
    unsigned wo0=LDW(r3,0),wo1=LDW(r3,1),wo2=LDW(r3,2),wo3=LDW(r3,3),wo4=LDW(r3,4);
    unsigned wo5=LDW(r3,5),wo6=LDW(r3,6),wo7=LDW(r3,7),wo8=LDW(r3,8),wo9=LDW(r3,9);
    unsigned wo10=LDW(r3,10),wo11=LDW(r3,11),wo12=LDW(r3,12),wo13=LDW(r3,13),wo14=LDW(r3,14);
    unsigned wo15=LDW(r3,15),wo16=LDW(r3,16),wo17=LDW(r3,17),wo18=LDW(r3,18),wo19=LDW(r3,19);
    unsigned wo20=LDW(r3,20),wo21=LDW(r3,21),wo22=LDW(r3,22),wo23=LDW(r3,23),wo24=LDW(r3,24);

    LA10(wi0,wi1,wi2,wi3,wi4,wi5,wi6,wi7,wi8,wi9);
    LA10(wi10,wi11,wi12,wi13,wi14,wi15,wi16,wi17,wi18,wi19);
    LA10(wi20,wi21,wi22,wi23,wi24,wf0,wf1,wf2,wf3,wf4);
    LA10(wf5,wf6,wf7,wf8,wf9,wf10,wf11,wf12,wf13,wf14);
    LA10(wf15,wf16,wf17,wf18,wf19,wf20,wf21,wf22,wf23,wf24);
    LA10(wg0,wg1,wg2,wg3,wg4,wg5,wg6,wg7,wg8,wg9);
    LA10(wg10,wg11,wg12,wg13,wg14,wg15,wg16,wg17,wg18,wg19);
    LA10(wg20,wg21,wg22,wg23,wg24,wo0,wo1,wo2,wo3,wo4);
    LA10(wo5,wo6,wo7,wo8,wo9,wo10,wo11,wo12,wo13,wo14);
    LA10(wo15,wo16,wo17,wo18,wo19,wo20,wo21,wo22,wo23,wo24);

    float hreg = 0.f, c = 0.f;
    if (lane < 50) {
        c    = c0[((long)dir * Bb + b) * Hh + lane];
        hreg = h0[((long)dir * Bb + b) * Hh + lane];
    }

    // packed h2 in lanes 0..24: (h[2u], h[2u+1])
    const int upk  = (lane < 25) ? lane : 24;
    const int idxA = (2 * upk) << 2;
    const int idxB = idxA + 4;
    #define BPERM(IDX) __uint_as_float((unsigned)__builtin_amdgcn_ds_bpermute((IDX), (int)__float_as_uint(hreg)))
    h2t hpk = PKH(BPERM(idxA), BPERM(idxB));

    const long rowbase = (long)b * Tt;
    const unsigned short* xbase = xg + rowbase * 400 + dir * 200 + u;
    float* op = xout + rowbase * 100 + dir * 50 + lane;

    #define TTOF(s) (dir ? (Tt - 1 - (s)) : (s))

    #define DD(K, WI, WF, WG, WO, AI, AF, AG, AO) { \
        h2t hh = __builtin_bit_cast(h2t, (unsigned)__builtin_amdgcn_readlane(hpki, K)); \
        DOT2(__builtin_bit_cast(h2t, WI), hh, AI); \
        DOT2(__builtin_bit_cast(h2t, WF), hh, AF); \
        DOT2(__builtin_bit_cast(h2t, WG), hh, AG); \
        DOT2(__builtin_bit_cast(h2t, WO), hh, AO); }

    #define STEP(QI, QF, QG, QO, TT) do { \
        float ai0 = BF(QI), ai1 = 0.f, af0 = BF(QF), af1 = 0.f; \
        float ag0 = BF(QG), ag1 = 0.f, ao0 = BF(QO), ao1 = 0.f; \
        const int hpki = (int)__builtin_bit_cast(unsigned, hpk); \
        DD(0,  wi0, wf0, wg0, wo0,  ai0,af0,ag0,ao0) \
        DD(1,  wi1, wf1, wg1, wo1,  ai1,af1,ag1,ao1) \
        DD(2,  wi2, wf2, wg2, wo2,  ai0,af0,ag0,ao0) \
        DD(3,  wi3, wf3, wg3, wo3,  ai1,af1,ag1,ao1) \
        DD(4,  wi4, wf4, wg4, wo4,  ai0,af0,ag0,ao0) \
        DD(5,  wi5, wf5, wg5, wo5,  ai1,af1,ag1,ao1) \
        DD(6,  wi6, wf6, wg6, wo6,  ai0,af0,ag0,ao0) \
        DD(7,  wi7, wf7, wg7, wo7,  ai1,af1,ag1,ao1) \
        DD(8,  wi8, wf8, wg8, wo8,  ai0,af0,ag0,ao0) \
        DD(9,  wi9, wf9, wg9, wo9,  ai1,af1,ag1,ao1) \
        DD(10, wi10,wf10,wg10,wo10, ai0,af0,ag0,ao0) \
        DD(11, wi11,wf11,wg11,wo11, ai1,af1,ag1,ao1) \
        DD(12, wi12,wf12,wg12,wo12, ai0,af0,ag0,ao0) \
        DD(13, wi13,wf13,wg13,wo13, ai1,af1,ag1,ao1) \
        DD(14, wi14,wf14,wg14,wo14, ai0,af0,ag0,ao0) \
        DD(15, wi15,wf15,wg15,wo15, ai1,af1,ag1,ao1) \
        DD(16, wi16,wf16,wg16,wo16, ai0,af0,ag0,ao0) \
        DD(17, wi17,wf17,wg17,wo17, ai1,af1,ag1,ao1) \
        DD(18, wi18,wf18,wg18,wo18, ai0,af0,ag0,ao0) \
        DD(19, wi19,wf19,wg19,wo19, ai1,af1,ag1,ao1) \
        DD(20, wi20,wf20,wg20,wo20, ai0,af0,ag0,ao0) \
        DD(21, wi21,wf21,wg21,wo21, ai1,af1,ag1,ao1) \
        DD(22, wi22,wf22,wg22,wo22, ai0,af0,ag0,ao0) \
        DD(23, wi23,wf23,wg23,wo23, ai1,af1,ag1,ao1) \
        DD(24, wi24,wf24,wg24,wo24, ai0,af0,ag0,ao0) \
        const float gi = fsig(ai0 + ai1); \
        const float gf = fsig(af0 + af1); \
        const float gc = ftanh(ag0 + ag1); \
        const float go = fsig(ao0 + ao1); \
        c = gf * c + gi * gc; \
        hreg = go * ftanh(c); \
        if (lane < 50) op[(long)(TT) * 100] = hreg; \
        hpk = PKH(BPERM(idxA), BPERM(idxB)); \
    } while (0)

    // 4-step prefetch queues (i,f,g,o per step), named scalars
    unsigned qa0, qb0, qc0, qd0, qa1, qb1, qc1, qd1;
    unsigned qa2, qb2, qc2, qd2, qa3, qb3, qc3, qd3;
    unsigned na0, nb0, nc0, nd0, na1, nb1, nc1, nd1;
    unsigned na2, nb2, nc2, nd2, na3, nb3, nc3, nd3;
    #define XL4(s, A, B, C, D) { \
        const unsigned short* p = xbase + (long)TTOF(s) * 400; \
        A = p[0]; B = p[50]; C = p[100]; D = p[150]; }
    XL4(0, qa0, qb0, qc0, qd0) XL4(1, qa1, qb1, qc1, qd1)
    XL4(2, qa2, qb2, qc2, qd2) XL4(3, qa3, qb3, qc3, qd3)
    na0=nb0=nc0=nd0=na1=nb1=nc1=nd1=0;
    na2=nb2=nc2=nd2=na3=nb3=nc3=nd3=0;

    for (int blk = 0; blk < Tt / 4; ++blk) {
        const int s0i = blk * 4;
        if (blk < Tt / 4 - 1) {
            XL4(s0i + 4, na0, nb0, nc0, nd0) XL4(s0i + 5, na1, nb1, nc1, nd1)
            XL4(s0i + 6, na2, nb2, nc2, nd2) XL4(s0i + 7, na3, nb3, nc3, nd3)
        }
        STEP(qa0, qb0, qc0, qd0, TTOF(s0i + 0));
        STEP(qa1, qb1, qc1, qd1, TTOF(s0i + 1));
        STEP(qa2, qb2, qc2, qd2, TTOF(s0i + 2));
        STEP(qa3, qb3, qc3, qd3, TTOF(s0i + 3));
        qa0=na0; qb0=nb0; qc0=nc0; qd0=nd0;
        qa1=na1; qb1=nb1; qc1=nc1; qd1=nd1;
        qa2=na2; qb2=nb2; qc2=nc2; qd2=nd2;
        qa3=na3; qb3=nb3; qc3=nc3; qd3=nd3;
    }
    #undef STEP
    #undef DD
    #undef XL4
    #undef TTOF
    #undef BPERM
}

// ---------------------------------------------------------------------------
// feats[row, i] = (x[row,:] . w_tag[i,:] + b_tag[i]) * mask[row], padded to 8
// ---------------------------------------------------------------------------
__global__ __launch_bounds__(256) void feats_kernel(
    const float* __restrict__ x,      // [M,100] fp32
    const float* __restrict__ w_tag,  // [7,100]
    const float* __restrict__ b_tag,  // [7]
    const float* __restrict__ mask,   // [M]
    float* __restrict__ feats)        // [M,8]
{
    const int gid = blockIdx.x * 256 + threadIdx.x;
    const int row = gid >> 3;
    const int i   = gid & 7;
    if (row >= Mrows) return;
    if (i == 7) { feats[(long)row * 8 + 7] = 0.f; return; }
    const float4* xr = (const float4*)(x + (long)row * 100);
    const float4* wr = (const float4*)(w_tag + (long)i * 100);
    float acc = b_tag[i];
    #pragma unroll
    for (int q = 0; q < 25; ++q) {
        float4 a = xr[q];
        float4 b = wr[q];
        acc += a.x * b.x + a.y * b.y + a.z * b.z + a.w * b.w;
    }
    feats[(long)row * 8 + i] = acc * mask[row];
}

// ---------------------------------------------------------------------------
// Viterbi forward. 8 lanes per batch row; backpointers packed [T][B].
// ---------------------------------------------------------------------------
__global__ __launch_bounds__(64) void viterbi_fwd(
    const float* __restrict__ feats,   // [M,8]
    const float* __restrict__ trans,   // [7,7]
    unsigned int* __restrict__ bptrw,  // [T*B]
    float* __restrict__ best_score,    // [B] -> d_out
    int* __restrict__ best_tag)        // [B] -> ws
{
    const int lane = threadIdx.x;
    const int sub  = lane >> 3;
    const int i    = lane & 7;
    const int b    = blockIdx.x * 8 + sub;
    const int base = lane & 56;

    float tr[7];
    #pragma unroll
    for (int j = 0; j < 7; ++j) tr[j] = (i < 7) ? trans[i * 7 + j] : -1e30f;

    float score = (i == START) ? 0.0f : NEGV;
    const long fb = (long)b * Tt;

    float featc = feats[(fb + 0) * 8 + i];
    for (int t = 0; t < Tt; ++t) {
        float featn = (t + 1 < Tt) ? feats[(fb + t + 1) * 8 + i] : 0.f;
        float best = -3.4e38f;
        int bp = 0;
        #pragma unroll
        for (int j = 0; j < 7; ++j) {
            float sj = __shfl(score, base | j, 64);
            float m = sj + tr[j];
            if (m > best) { best = m; bp = j; }
        }
        if (i < 7) score = best + featc;
        unsigned v = (i < 7) ? ((unsigned)bp << (3 * i)) : 0u;
        v |= __shfl_xor(v, 1, 64);
        v |= __shfl_xor(v, 2, 64);
        v |= __shfl_xor(v, 4, 64);
        if (i == 0) bptrw[(long)t * Bb + b] = v;
        featc = featn;
    }

    float bestv = score;
    int bt = 0;
    #pragma unroll
    for (int j = 1; j < 7; ++j) {
        float sj = __shfl(score, base | j, 64);
        if (i == 0 && sj > bestv) { bestv = sj; bt = j; }
    }
    if (i == 0) {
        best_score[b] = bestv;
        best_tag[b]   = bt;
    }
}

// ---------------------------------------------------------------------------
__global__ __launch_bounds__(128) void backtrack(
    const unsigned int* __restrict__ bptrw,
    const int* __restrict__ best_tag,
    float* __restrict__ out_tags)   // d_out + 128, [B,T]
{
    const int b = threadIdx.x;
    if (b >= Bb) return;
    const long fb = (long)b * Tt;
    int tag = best_tag[b];
    out_tags[fb + Tt - 1] = (float)tag;
    #pragma unroll 8
    for (int t = Tt - 1; t >= 1; --t) {
        unsigned w = bptrw[(long)t * Bb + b];
        tag = (w >> (3 * tag)) & 7;
        out_tags[fb + t - 1] = (float)tag;
    }
}

// ---------------------------------------------------------------------------
extern "C" void kernel_launch(void* const* d_in, const int* in_sizes, int n_in,
                              void* d_out, int out_size, void* d_ws, size_t ws_size,
                              hipStream_t stream)
{
    const int*   sent    = (const int*)  d_in[0];
    const float* mask    = (const float*)d_in[1];
    const float* emb     = (const float*)d_in[2];
    const float* h0      = (const float*)d_in[3];
    const float* c0      = (const float*)d_in[4];
    const float* w_ih_l0 = (const float*)d_in[5];
    const float* w_hh_l0 = (const float*)d_in[6];
    const float* b_l0    = (const float*)d_in[7];
    const float* w_ih_l1 = (const float*)d_in[8];
    const float* w_hh_l1 = (const float*)d_in[9];
    const float* b_l1    = (const float*)d_in[10];
    const float* w_ih_l2 = (const float*)d_in[11];
    const float* w_hh_l2 = (const float*)d_in[12];
    const float* b_l2    = (const float*)d_in[13];
    const float* w_tag   = (const float*)d_in[14];
    const float* b_tag   = (const float*)d_in[15];
    const float* trans   = (const float*)d_in[16];

    float* out = (float*)d_out;
    char* ws = (char*)d_ws;

    // workspace layout (bytes)
    unsigned short* xg    = (unsigned short*)(ws);                    // 52,428,800
    float*          xa    = (float*)(ws + 52428800L);                 // 26,214,400
    float*          xb    = (float*)(ws + 78643200L);                 // 26,214,400
    unsigned short* AbR   = (unsigned short*)(ws + 104857600L);       // 41,943,040
    float*          feats = (float*)(ws + 146800640L);                //  2,097,152
    unsigned*       bptrw = (unsigned*)(ws + 148897792L);             //    262,144
    unsigned short* Wb0   = (unsigned short*)(ws + 149159936L);       //    286,720
    unsigned short* Wb1   = (unsigned short*)(ws + 149446656L);       //    114,688
    unsigned short* Wb2   = (unsigned short*)(ws + 149561344L);       //    114,688
    int*            btag  = (int*)(ws + 149676032L);                  //        512

    dim3 gridG(Mrows / 128, 7);   // 128x64 tiles over [65536, 448]

    // weight conversions (independent)
    conv_w<<<(448 * 320 + 255) / 256, 256, 0, stream>>>(w_ih_l0, Wb0, 300, 320);
    conv_w<<<(448 * 128 + 255) / 256, 256, 0, stream>>>(w_ih_l1, Wb1, 100, 128);
    conv_w<<<(448 * 128 + 255) / 256, 256, 0, stream>>>(w_ih_l2, Wb2, 100, 128);

    // layer 0
    conv_a<true><<<(Mrows * 40 + 255) / 256, 256, 0, stream>>>(emb, sent, AbR, 300, 320, 40);
    gemm_mfma<<<gridG, 256, 0, stream>>>(AbR, Wb0, b_l0, xg, 320);
    lstm_scan<<<256, 64, 0, stream>>>(xg, w_hh_l0, h0 + 0 * Bb * Hh, c0 + 0 * Bb * Hh, xa);

    // layer 1
    conv_a<false><<<(Mrows * 16 + 255) / 256, 256, 0, stream>>>(xa, nullptr, AbR, 100, 128, 16);
    gemm_mfma<<<gridG, 256, 0, stream>>>(AbR, Wb1, b_l1, xg, 128);
    lstm_scan<<<256, 64, 0, stream>>>(xg, w_hh_l1, h0 + 2 * Bb * Hh, c0 + 2 * Bb * Hh, xb);

    // layer 2
    conv_a<false><<<(Mrows * 16 + 255) / 256, 256, 0, stream>>>(xb, nullptr, AbR, 100, 128, 16);
    gemm_mfma<<<gridG, 256, 0, stream>>>(AbR, Wb2, b_l2, xg, 128);
    lstm_scan<<<256, 64, 0, stream>>>(xg, w_hh_l2, h0 + 4 * Bb * Hh, c0 + 4 * Bb * Hh, xa);

    // tag projection + viterbi + backtrace
    feats_kernel<<<Mrows * 8 / 256, 256, 0, stream>>>(xa, w_tag, b_tag, mask, feats);
    viterbi_fwd<<<Bb / 8, 64, 0, stream>>>(feats, trans, bptrw, out, btag);
    backtrack<<<1, 128, 0, stream>>>(bptrw, btag, out + Bb);
}

// Round 15
// 1194.932 us; speedup vs baseline: 1.0440x; 1.0440x over previous
//
#include <hip/hip_runtime.h>

#define NEGV (-10000.0f)

static constexpr int Bb    = 128;
static constexpr int Tt    = 512;
static constexpr int Mrows = Bb * Tt;   // 65536
static constexpr int Hh    = 50;
static constexpr int START = 5;

typedef __attribute__((ext_vector_type(8))) short bf16x8;
typedef __attribute__((ext_vector_type(4))) float f32x4;

__device__ __forceinline__ float fsig(float x) {
    return __builtin_amdgcn_rcpf(1.0f + __expf(-x));
}
__device__ __forceinline__ float ftanh(float x) {
    return 2.0f * __builtin_amdgcn_rcpf(1.0f + __expf(-2.0f * x)) - 1.0f;
}
__device__ __forceinline__ unsigned short f2bf(float f) {
    unsigned u = __float_as_uint(f);
    u = (u + 0x7fffu + ((u >> 16) & 1u)) >> 16;   // RNE
    return (unsigned short)u;
}
#define BF(u) __uint_as_float(((unsigned)(u)) << 16)

// ---------------------------------------------------------------------------
// Convert W [400][K] fp32 -> [448][KP] bf16 (zero-padded rows/cols)
// ---------------------------------------------------------------------------
__global__ __launch_bounds__(256) void conv_w(
    const float* __restrict__ src, unsigned short* __restrict__ dst,
    int K, int KP)
{
    int gid = blockIdx.x * 256 + threadIdx.x;
    int tot = 448 * KP;
    if (gid >= tot) return;
    int r = gid / KP, c = gid % KP;
    float v = (r < 400 && c < K) ? src[r * K + c] : 0.f;
    dst[gid] = f2bf(v);
}

// ---------------------------------------------------------------------------
// Convert A rows (gathered, layer 0 only) fp32 -> [M][KP] bf16
// ---------------------------------------------------------------------------
template <bool GATHER>
__global__ __launch_bounds__(256) void conv_a(
    const float* __restrict__ src, const int* __restrict__ idx,
    unsigned short* __restrict__ dst, int K, int KP, int cpr)
{
    long gid = (long)blockIdx.x * 256 + threadIdx.x;
    long tot = (long)Mrows * cpr;
    if (gid >= tot) return;
    long m = gid / cpr;
    int p = (int)(gid - m * cpr) * 8;
    const float* s = src + (GATHER ? (long)idx[m] : m) * K;
    unsigned u0, u1, u2, u3;
    {
        float x0 = (p + 0 < K) ? s[p + 0] : 0.f;
        float x1 = (p + 1 < K) ? s[p + 1] : 0.f;
        float x2 = (p + 2 < K) ? s[p + 2] : 0.f;
        float x3 = (p + 3 < K) ? s[p + 3] : 0.f;
        float x4 = (p + 4 < K) ? s[p + 4] : 0.f;
        float x5 = (p + 5 < K) ? s[p + 5] : 0.f;
        float x6 = (p + 6 < K) ? s[p + 6] : 0.f;
        float x7 = (p + 7 < K) ? s[p + 7] : 0.f;
        u0 = (unsigned)f2bf(x0) | ((unsigned)f2bf(x1) << 16);
        u1 = (unsigned)f2bf(x2) | ((unsigned)f2bf(x3) << 16);
        u2 = (unsigned)f2bf(x4) | ((unsigned)f2bf(x5) << 16);
        u3 = (unsigned)f2bf(x6) | ((unsigned)f2bf(x7) << 16);
    }
    uint4 v = make_uint4(u0, u1, u2, u3);
    *(uint4*)(dst + m * KP + p) = v;
}

// ---------------------------------------------------------------------------
// bf16 MFMA GEMM: C[M,400]bf16 = A[M,KP]bf16 @ W[448,KP]bf16^T + bias
// (unchanged from r10/r11, verified)
// ---------------------------------------------------------------------------
__global__ __launch_bounds__(256) void gemm_mfma(
    const unsigned short* __restrict__ Ab,   // [M][KP]
    const unsigned short* __restrict__ Wb,   // [448][KP]
    const float* __restrict__ bias,          // [400]
    unsigned short* __restrict__ C,          // [M][400] bf16
    int KP)
{
    __shared__ unsigned short As[128][40];
    __shared__ unsigned short Ws[64][40];

    const int tid = threadIdx.x;
    const int m0 = blockIdx.x * 128;
    const int n0 = blockIdx.y * 64;

    const int w  = tid >> 6, l = tid & 63;
    const int wm = (w >> 1) * 64;
    const int wn = (w & 1) * 32;
    const int lr = l & 15;
    const int lk = (l >> 4) * 8;

    f32x4 acc[4][2] = {};

    for (int k0 = 0; k0 < KP; k0 += 32) {
        __syncthreads();
        {
            int c = tid;
            int r = c >> 2, p = (c & 3) * 8;
            *(bf16x8*)&As[r][p] = *(const bf16x8*)(Ab + (long)(m0 + r) * KP + k0 + p);
            c = tid + 256;
            r = c >> 2; p = (c & 3) * 8;
            *(bf16x8*)&As[r][p] = *(const bf16x8*)(Ab + (long)(m0 + r) * KP + k0 + p);
            r = tid >> 2; p = (tid & 3) * 8;
            *(bf16x8*)&Ws[r][p] = *(const bf16x8*)(Wb + (long)(n0 + r) * KP + k0 + p);
        }
        __syncthreads();

        bf16x8 af0 = *(const bf16x8*)&As[wm +  0 + lr][lk];
        bf16x8 af1 = *(const bf16x8*)&As[wm + 16 + lr][lk];
        bf16x8 af2 = *(const bf16x8*)&As[wm + 32 + lr][lk];
        bf16x8 af3 = *(const bf16x8*)&As[wm + 48 + lr][lk];
        bf16x8 wf0 = *(const bf16x8*)&Ws[wn +  0 + lr][lk];
        bf16x8 wf1 = *(const bf16x8*)&Ws[wn + 16 + lr][lk];

        acc[0][0] = __builtin_amdgcn_mfma_f32_16x16x32_bf16(af0, wf0, acc[0][0], 0, 0, 0);
        acc[0][1] = __builtin_amdgcn_mfma_f32_16x16x32_bf16(af0, wf1, acc[0][1], 0, 0, 0);
        acc[1][0] = __builtin_amdgcn_mfma_f32_16x16x32_bf16(af1, wf0, acc[1][0], 0, 0, 0);
        acc[1][1] = __builtin_amdgcn_mfma_f32_16x16x32_bf16(af1, wf1, acc[1][1], 0, 0, 0);
        acc[2][0] = __builtin_amdgcn_mfma_f32_16x16x32_bf16(af2, wf0, acc[2][0], 0, 0, 0);
        acc[2][1] = __builtin_amdgcn_mfma_f32_16x16x32_bf16(af2, wf1, acc[2][1], 0, 0, 0);
        acc[3][0] = __builtin_amdgcn_mfma_f32_16x16x32_bf16(af3, wf0, acc[3][0], 0, 0, 0);
        acc[3][1] = __builtin_amdgcn_mfma_f32_16x16x32_bf16(af3, wf1, acc[3][1], 0, 0, 0);
    }

    const int orow = (l >> 4) * 4;
    const int ocol = l & 15;
    #pragma unroll
    for (int a = 0; a < 4; ++a) {
        #pragma unroll
        for (int bb = 0; bb < 2; ++bb) {
            const int col = n0 + wn + bb * 16 + ocol;
            if (col < 400) {
                const float bv = bias[col];
                #pragma unroll
                for (int i = 0; i < 4; ++i) {
                    const long row = m0 + wm + a * 16 + orow + i;
                    C[row * 400 + col] = f2bf(acc[a][bb][i] + bv);
                }
            }
        }
    }
}

// ---------------------------------------------------------------------------
// LSTM scan: EXACT r11 structure (passed @268us/scan): 4 waves, gate-major,
// 50 laundered fp32 scalar weights/thread, h via v_readlane, pre[2][200]
// double-buffered, one raw s_barrier/step (lgkm-only drain).
// ONLY change vs r11: output written as bf16 into the [M,128] padded GEMM
// A-layout (lanes 50-63 of wave 0 write the zero pad) -> deletes conv_a
// for layers 1/2 and halves the scan's output write traffic.
// ---------------------------------------------------------------------------
#define H(J) __uint_as_float((unsigned)__builtin_amdgcn_readlane((int)__float_as_uint(hreg), (J)))

__global__ void
__attribute__((amdgpu_flat_work_group_size(256, 256), amdgpu_waves_per_eu(1, 1)))
lstm_scan(
    const unsigned short* __restrict__ xg,  // [M,400] bf16 (bias added)
    const float* __restrict__ w_hh,         // [2,200,50]
    const float* __restrict__ h0,           // layer base: [2,B,50]
    const float* __restrict__ c0,
    unsigned short* __restrict__ xout)      // [M,128] bf16, cols 100-127 = 0
{
    const int b    = blockIdx.x & 127;
    const int dir  = blockIdx.x >> 7;
    const int tid  = threadIdx.x;
    const int lane = tid & 63;
    const int wv   = tid >> 6;

    __shared__ float pre[2][200];   // double-buffered pre-gates (only LDS)

    const int gr = (tid < 200) ? tid : 199;

    const float* wr = w_hh + ((long)dir * 200 + gr) * 50;
    float w0  = wr[0],  w1  = wr[1],  w2  = wr[2],  w3  = wr[3],  w4  = wr[4];
    float w5  = wr[5],  w6  = wr[6],  w7  = wr[7],  w8  = wr[8],  w9  = wr[9];
    float w10 = wr[10], w11 = wr[11], w12 = wr[12], w13 = wr[13], w14 = wr[14];
    float w15 = wr[15], w16 = wr[16], w17 = wr[17], w18 = wr[18], w19 = wr[19];
    float w20 = wr[20], w21 = wr[21], w22 = wr[22], w23 = wr[23], w24 = wr[24];
    float w25 = wr[25], w26 = wr[26], w27 = wr[27], w28 = wr[28], w29 = wr[29];
    float w30 = wr[30], w31 = wr[31], w32 = wr[32], w33 = wr[33], w34 = wr[34];
    float w35 = wr[35], w36 = wr[36], w37 = wr[37], w38 = wr[38], w39 = wr[39];
    float w40 = wr[40], w41 = wr[41], w42 = wr[42], w43 = wr[43], w44 = wr[44];
    float w45 = wr[45], w46 = wr[46], w47 = wr[47], w48 = wr[48], w49 = wr[49];
    asm volatile("" : "+v"(w0), "+v"(w1), "+v"(w2), "+v"(w3), "+v"(w4),
                      "+v"(w5), "+v"(w6), "+v"(w7), "+v"(w8), "+v"(w9));
    asm volatile("" : "+v"(w10), "+v"(w11), "+v"(w12), "+v"(w13), "+v"(w14),
                      "+v"(w15), "+v"(w16), "+v"(w17), "+v"(w18), "+v"(w19));
    asm volatile("" : "+v"(w20), "+v"(w21), "+v"(w22), "+v"(w23), "+v"(w24),
                      "+v"(w25), "+v"(w26), "+v"(w27), "+v"(w28), "+v"(w29));
    asm volatile("" : "+v"(w30), "+v"(w31), "+v"(w32), "+v"(w33), "+v"(w34),
                      "+v"(w35), "+v"(w36), "+v"(w37), "+v"(w38), "+v"(w39));
    asm volatile("" : "+v"(w40), "+v"(w41), "+v"(w42), "+v"(w43), "+v"(w44),
                      "+v"(w45), "+v"(w46), "+v"(w47), "+v"(w48), "+v"(w49));

    // h and c live in registers of lanes 0-49 of EVERY wave (redundant).
    float hreg = 0.f, c = 0.f;
    if (lane < 50) {
        c    = c0[((long)dir * Bb + b) * Hh + lane];
        hreg = h0[((long)dir * Bb + b) * Hh + lane];
    }
    __syncthreads();

    const long rowbase = (long)b * Tt;
    const unsigned short* xbase = xg + rowbase * 400 + dir * 200 + gr;
    // output col: units -> dir*50+lane; pad cols 100-127 split across dirs
    const int ocol = (lane < 50) ? (dir * 50 + lane) : (100 + dir * 14 + (lane - 50));
    unsigned short* op = xout + rowbase * 128 + ocol;

    #define XLD(s)  xbase[(long)(dir ? (Tt - 1 - (s)) : (s)) * 400]
    #define TTOF(s) (dir ? (Tt - 1 - (s)) : (s))

    #define STEP(PRE, XIN, TT) do {                                         \
        if (tid < 200) {                                                    \
            float s0 = BF(XIN), s1 = 0.f, s2 = 0.f, s3 = 0.f;               \
            s0 += w0 *H(0);  s1 += w1 *H(1);  s2 += w2 *H(2);  s3 += w3 *H(3);  \
            s0 += w4 *H(4);  s1 += w5 *H(5);  s2 += w6 *H(6);  s3 += w7 *H(7);  \
            s0 += w8 *H(8);  s1 += w9 *H(9);  s2 += w10*H(10); s3 += w11*H(11); \
            s0 += w12*H(12); s1 += w13*H(13); s2 += w14*H(14); s3 += w15*H(15); \
            s0 += w16*H(16); s1 += w17*H(17); s2 += w18*H(18); s3 += w19*H(19); \
            s0 += w20*H(20); s1 += w21*H(21); s2 += w22*H(22); s3 += w23*H(23); \
            s0 += w24*H(24); s1 += w25*H(25); s2 += w26*H(26); s3 += w27*H(27); \
            s0 += w28*H(28); s1 += w29*H(29); s2 += w30*H(30); s3 += w31*H(31); \
            s0 += w32*H(32); s1 += w33*H(33); s2 += w34*H(34); s3 += w35*H(35); \
            s0 += w36*H(36); s1 += w37*H(37); s2 += w38*H(38); s3 += w39*H(39); \
            s0 += w40*H(40); s1 += w41*H(41); s2 += w42*H(42); s3 += w43*H(43); \
            s0 += w44*H(44); s1 += w45*H(45); s2 += w46*H(46); s3 += w47*H(47); \
            s0 += w48*H(48); s1 += w49*H(49);                               \
            (PRE)[tid] = (s0 + s1) + (s2 + s3);                             \
        }                                                                   \
        asm volatile("s_waitcnt lgkmcnt(0)\n\ts_barrier" ::: "memory");     \
        {                                                                   \
            unsigned short val = 0;                                         \
            if (lane < 50) {                                                \
                const float gi = fsig((PRE)[lane]);                         \
                const float gf = fsig((PRE)[50 + lane]);                    \
                const float gc = ftanh((PRE)[100 + lane]);                  \
                const float go = fsig((PRE)[150 + lane]);                   \
                c = gf * c + gi * gc;                                       \
                hreg = go * ftanh(c);                                       \
                val = f2bf(hreg);                                           \
            }                                                               \
            if (wv == 0) op[(long)(TT) * 128] = val;                        \
        }                                                                   \
    } while (0)

    unsigned xc0 = XLD(0), xc1 = XLD(1), xc2 = XLD(2), xc3 = XLD(3);
    unsigned xn0 = 0, xn1 = 0, xn2 = 0, xn3 = 0;

    for (int blk = 0; blk < Tt / 4; ++blk) {
        const int s0i = blk * 4;
        if (blk < Tt / 4 - 1) {
            xn0 = XLD(s0i + 4); xn1 = XLD(s0i + 5);
            xn2 = XLD(s0i + 6); xn3 = XLD(s0i + 7);
        }
        STEP(pre[0], xc0, TTOF(s0i + 0));
        STEP(pre[1], xc1, TTOF(s0i + 1));
        STEP(pre[0], xc2, TTOF(s0i + 2));
        STEP(pre[1], xc3, TTOF(s0i + 3));
        xc0 = xn0; xc1 = xn1; xc2 = xn2; xc3 = xn3;
    }
    #undef STEP
    #undef XLD
    #undef TTOF
}

// ---------------------------------------------------------------------------
// feats[row, i] = (x_bf16[row,:100] . w_tag[i,:] + b_tag[i]) * mask[row]
// ---------------------------------------------------------------------------
__global__ __launch_bounds__(256) void feats_kernel(
    const unsigned short* __restrict__ x, // [M,128] bf16
    const float* __restrict__ w_tag,      // [7,100]
    const float* __restrict__ b_tag,      // [7]
    const float* __restrict__ mask,       // [M]
    float* __restrict__ feats)            // [M,8]
{
    const int gid = blockIdx.x * 256 + threadIdx.x;
    const int row = gid >> 3;
    const int i   = gid & 7;
    if (row >= Mrows) return;
    if (i == 7) { feats[(long)row * 8 + 7] = 0.f; return; }
    const unsigned* xr = (const unsigned*)(x + (long)row * 128); // 2 bf16/word
    const float* wr = w_tag + i * 100;
    float acc = b_tag[i];
    #pragma unroll
    for (int q = 0; q < 50; ++q) {
        unsigned v = xr[q];
        float2 w2 = *(const float2*)(wr + 2 * q);
        acc += __uint_as_float(v << 16) * w2.x
             + __uint_as_float(v & 0xffff0000u) * w2.y;
    }
    feats[(long)row * 8 + i] = acc * mask[row];
}

// ---------------------------------------------------------------------------
// Viterbi forward. 8 lanes per batch row; backpointers packed [T][B].
// ---------------------------------------------------------------------------
__global__ __launch_bounds__(64) void viterbi_fwd(
    const float* __restrict__ feats,   // [M,8]
    const float* __restrict__ trans,   // [7,7]
    unsigned int* __restrict__ bptrw,  // [T*B]
    float* __restrict__ best_score,    // [B] -> d_out
    int* __restrict__ best_tag)        // [B] -> ws
{
    const int lane = threadIdx.x;
    const int sub  = lane >> 3;
    const int i    = lane & 7;
    const int b    = blockIdx.x * 8 + sub;
    const int base = lane & 56;

    float tr[7];
    #pragma unroll
    for (int j = 0; j < 7; ++j) tr[j] = (i < 7) ? trans[i * 7 + j] : -1e30f;

    float score = (i == START) ? 0.0f : NEGV;
    const long fb = (long)b * Tt;

    float featc = feats[(fb + 0) * 8 + i];
    for (int t = 0; t < Tt; ++t) {
        float featn = (t + 1 < Tt) ? feats[(fb + t + 1) * 8 + i] : 0.f;
        float best = -3.4e38f;
        int bp = 0;
        #pragma unroll
        for (int j = 0; j < 7; ++j) {
            float sj = __shfl(score, base | j, 64);
            float m = sj + tr[j];
            if (m > best) { best = m; bp = j; }
        }
        if (i < 7) score = best + featc;
        unsigned v = (i < 7) ? ((unsigned)bp << (3 * i)) : 0u;
        v |= __shfl_xor(v, 1, 64);
        v |= __shfl_xor(v, 2, 64);
        v |= __shfl_xor(v, 4, 64);
        if (i == 0) bptrw[(long)t * Bb + b] = v;
        featc = featn;
    }

    float bestv = score;
    int bt = 0;
    #pragma unroll
    for (int j = 1; j < 7; ++j) {
        float sj = __shfl(score, base | j, 64);
        if (i == 0 && sj > bestv) { bestv = sj; bt = j; }
    }
    if (i == 0) {
        best_score[b] = bestv;
        best_tag[b]   = bt;
    }
}

// ---------------------------------------------------------------------------
__global__ __launch_bounds__(128) void backtrack(
    const unsigned int* __restrict__ bptrw,
    const int* __restrict__ best_tag,
    float* __restrict__ out_tags)   // d_out + 128, [B,T]
{
    const int b = threadIdx.x;
    if (b >= Bb) return;
    const long fb = (long)b * Tt;
    int tag = best_tag[b];
    out_tags[fb + Tt - 1] = (float)tag;
    #pragma unroll 8
    for (int t = Tt - 1; t >= 1; --t) {
        unsigned w = bptrw[(long)t * Bb + b];
        tag = (w >> (3 * tag)) & 7;
        out_tags[fb + t - 1] = (float)tag;
    }
}

// ---------------------------------------------------------------------------
extern "C" void kernel_launch(void* const* d_in, const int* in_sizes, int n_in,
                              void* d_out, int out_size, void* d_ws, size_t ws_size,
                              hipStream_t stream)
{
    const int*   sent    = (const int*)  d_in[0];
    const float* mask    = (const float*)d_in[1];
    const float* emb     = (const float*)d_in[2];
    const float* h0      = (const float*)d_in[3];
    const float* c0      = (const float*)d_in[4];
    const float* w_ih_l0 = (const float*)d_in[5];
    const float* w_hh_l0 = (const float*)d_in[6];
    const float* b_l0    = (const float*)d_in[7];
    const float* w_ih_l1 = (const float*)d_in[8];
    const float* w_hh_l1 = (const float*)d_in[9];
    const float* b_l1    = (const float*)d_in[10];
    const float* w_ih_l2 = (const float*)d_in[11];
    const float* w_hh_l2 = (const float*)d_in[12];
    const float* b_l2    = (const float*)d_in[13];
    const float* w_tag   = (const float*)d_in[14];
    const float* b_tag   = (const float*)d_in[15];
    const float* trans   = (const float*)d_in[16];

    float* out = (float*)d_out;
    char* ws = (char*)d_ws;

    // workspace layout (bytes)
    unsigned short* xg    = (unsigned short*)(ws);                  // 52,428,800
    unsigned short* xa16  = (unsigned short*)(ws + 52428800L);      // 16,777,216
    unsigned short* xb16  = (unsigned short*)(ws + 69206016L);      // 16,777,216
    unsigned short* AbR   = (unsigned short*)(ws + 85983232L);      // 41,943,040
    float*          feats = (float*)(ws + 127926272L);              //  2,097,152
    unsigned*       bptrw = (unsigned*)(ws + 130023424L);           //    262,144
    unsigned short* Wb0   = (unsigned short*)(ws + 130285568L);     //    286,720
    unsigned short* Wb1   = (unsigned short*)(ws + 130572288L);     //    114,688
    unsigned short* Wb2   = (unsigned short*)(ws + 130686976L);     //    114,688
    int*            btag  = (int*)(ws + 130801664L);                //        512

    dim3 gridG(Mrows / 128, 7);   // 128x64 tiles over [65536, 448]

    // weight conversions (independent)
    conv_w<<<(448 * 320 + 255) / 256, 256, 0, stream>>>(w_ih_l0, Wb0, 300, 320);
    conv_w<<<(448 * 128 + 255) / 256, 256, 0, stream>>>(w_ih_l1, Wb1, 100, 128);
    conv_w<<<(448 * 128 + 255) / 256, 256, 0, stream>>>(w_ih_l2, Wb2, 100, 128);

    // layer 0 (embedding gather -> bf16)
    conv_a<true><<<(Mrows * 40 + 255) / 256, 256, 0, stream>>>(emb, sent, AbR, 300, 320, 40);
    gemm_mfma<<<gridG, 256, 0, stream>>>(AbR, Wb0, b_l0, xg, 320);
    lstm_scan<<<256, 256, 0, stream>>>(xg, w_hh_l0, h0 + 0 * Bb * Hh, c0 + 0 * Bb * Hh, xa16);

    // layer 1 (scan output already in bf16 [M,128] A-layout)
    gemm_mfma<<<gridG, 256, 0, stream>>>(xa16, Wb1, b_l1, xg, 128);
    lstm_scan<<<256, 256, 0, stream>>>(xg, w_hh_l1, h0 + 2 * Bb * Hh, c0 + 2 * Bb * Hh, xb16);

    // layer 2
    gemm_mfma<<<gridG, 256, 0, stream>>>(xb16, Wb2, b_l2, xg, 128);
    lstm_scan<<<256, 256, 0, stream>>>(xg, w_hh_l2, h0 + 4 * Bb * Hh, c0 + 4 * Bb * Hh, xa16);

    // tag projection + viterbi + backtrace
    feats_kernel<<<Mrows * 8 / 256, 256, 0, stream>>>(xa16, w_tag, b_tag, mask, feats);
    viterbi_fwd<<<Bb / 8, 64, 0, stream>>>(feats, trans, bptrw, out, btag);
    backtrack<<<1, 128, 0, stream>>>(bptrw, btag, out + Bb);
}